// Round 6
// baseline (446.047 us; speedup 1.0000x reference)
//
#include <hip/hip_runtime.h>

typedef short bf16x8 __attribute__((ext_vector_type(8)));
typedef float f32x4 __attribute__((ext_vector_type(4)));

#define MASK_NEG (-1e30f)

__device__ __forceinline__ unsigned short f2bf(float f) {
  union { float f; unsigned u; } v; v.f = f;
  unsigned r = v.u + 0x7fffu + ((v.u >> 16) & 1u);
  return (unsigned short)(r >> 16);
}

__device__ __forceinline__ void gl_lds16(const void* g, void* l) {
  __builtin_amdgcn_global_load_lds(
      (__attribute__((address_space(1))) void*)(void*)g,
      (__attribute__((address_space(3))) void*)l, 16, 0, 0);
}

// -------- shared transpose body: dst[c][r] = bf16(src[r][c]), 64x64 tile ----
__device__ __forceinline__ void transpose_tile(
    const float* __restrict__ s, unsigned short* __restrict__ d,
    int R, int C, int x0, int y0, int t, float tile[64][65]) {
  {
    const int r = t >> 4, c4 = (t & 15) * 4;
    for (int it = 0; it < 4; ++it) {
      const int rr = r + it * 16;
      const float4 v = *(const float4*)(s + (size_t)(y0 + rr) * C + x0 + c4);
      tile[rr][c4 + 0] = v.x; tile[rr][c4 + 1] = v.y;
      tile[rr][c4 + 2] = v.z; tile[rr][c4 + 3] = v.w;
    }
  }
  __syncthreads();
  {
    const int cc = t >> 4, r4 = (t & 15) * 4;
    for (int it = 0; it < 4; ++it) {
      const int c = cc + it * 16;
      ushort4 o;
      o.x = f2bf(tile[r4 + 0][c]); o.y = f2bf(tile[r4 + 1][c]);
      o.z = f2bf(tile[r4 + 2][c]); o.w = f2bf(tile[r4 + 3][c]);
      *(ushort4*)(d + (size_t)(x0 + c) * R + y0 + r4) = o;
    }
  }
}

// -------- transpose x (8 batches) + Wo, all 1024x1024, one dispatch --------
__global__ __launch_bounds__(256) void transpose_x_wo(
    const float* __restrict__ x, const float* __restrict__ Wo,
    unsigned short* __restrict__ xt, unsigned short* __restrict__ Wot) {
  __shared__ float tile[64][65];
  const int z = blockIdx.z;   // 0..7: x batch, 8: Wo
  const float* s = (z < 8) ? (x + (size_t)z * 1048576) : Wo;
  unsigned short* d = (z < 8) ? (xt + (size_t)z * 1048576) : Wot;
  transpose_tile(s, d, 1024, 1024, blockIdx.x * 64, blockIdx.y * 64,
                 threadIdx.x, tile);
}

// -------- transpose all 24 per-head W matrices (1024x128) in one dispatch ---
__global__ __launch_bounds__(256) void transpose_w24(
    const float* __restrict__ Wq, const float* __restrict__ Wk,
    const float* __restrict__ Wv, unsigned short* __restrict__ WqkvT) {
  __shared__ float tile[64][65];
  const int z = blockIdx.z;   // 0..23
  const int sel = z >> 3, h = z & 7;
  const float* base = (sel == 0) ? Wq : (sel == 1) ? Wk : Wv;
  const float* s = base + (size_t)h * 131072;
  unsigned short* d = WqkvT + (size_t)z * 131072;
  transpose_tile(s, d, 1024, 128, blockIdx.x * 64, blockIdx.y * 64,
                 threadIdx.x, tile);
}

// -------- generic bf16 MFMA GEMM, BK=64 (m97 staging) -----------------------
// C[M,N] = scale * A[M,K] * B[N,K]^T ; A,B K-contiguous; K % 64 == 0.
// Chunked XCD swizzle when nwg % 8 == 0 (T1). If Vt != null and gh >= 16,
// the block's output is written TRANSPOSED (bf16) into Vt[(gb*8+gh-16)][col][row]
// instead of C (used by the QKV GEMM to produce V' = V^T directly).
template<bool F32OUT>
__global__ __launch_bounds__(256) void gemm_tn(
    const unsigned short* __restrict__ A, const unsigned short* __restrict__ B,
    void* __restrict__ Cv,
    int K, int ldA, int ldB, int ldC, float scale,
    long sAl, long sAb, long sAh,
    long sBl, long sBb, long sBh,
    long sCl, long sCb, long sCh,
    int zbase, int zdiv, unsigned short* __restrict__ Vt)
{
  __shared__ unsigned short As[128 * 64];   // [128 rows][64 k], chunk-swizzled
  __shared__ unsigned short Bs[128 * 64];
  int bx, by, bz;
  {
    const int nx = gridDim.x, ny = gridDim.y;
    const int nwg = nx * ny * gridDim.z;
    int flat = blockIdx.x + nx * (blockIdx.y + ny * blockIdx.z);
    if ((nwg & 7) == 0) flat = (flat & 7) * (nwg >> 3) + (flat >> 3);
    bx = flat % nx; flat /= nx;
    by = flat % ny; bz = flat / ny;
  }
  const int z = bz;
  const int g = zbase + z;
  const int gb = g / zdiv, gh = g % zdiv;
  const unsigned short* Ab = A + (size_t)z * sAl + (size_t)gb * sAb + (size_t)gh * sAh;
  const unsigned short* Bb = B + (size_t)z * sBl + (size_t)gb * sBb + (size_t)gh * sBh;
  const int m0 = by * 128, n0 = bx * 128;
  const int t = threadIdx.x;
  const int lane = t & 63;
  const int wave = t >> 6;
  const int wm = wave >> 1, wn = wave & 1;

  const int sr2 = t >> 3;          // 0..31
  const int ss8 = t & 7;
  const int sq8 = ss8 ^ (sr2 & 7);

  const unsigned short* ap0 = Ab + (size_t)(m0 +  0 + sr2) * ldA + sq8 * 8;
  const unsigned short* ap1 = Ab + (size_t)(m0 + 32 + sr2) * ldA + sq8 * 8;
  const unsigned short* ap2 = Ab + (size_t)(m0 + 64 + sr2) * ldA + sq8 * 8;
  const unsigned short* ap3 = Ab + (size_t)(m0 + 96 + sr2) * ldA + sq8 * 8;
  const unsigned short* bp0 = Bb + (size_t)(n0 +  0 + sr2) * ldB + sq8 * 8;
  const unsigned short* bp1 = Bb + (size_t)(n0 + 32 + sr2) * ldB + sq8 * 8;
  const unsigned short* bp2 = Bb + (size_t)(n0 + 64 + sr2) * ldB + sq8 * 8;
  const unsigned short* bp3 = Bb + (size_t)(n0 + 96 + sr2) * ldB + sq8 * 8;

  char* asd0 = (char*)As +     0 + t * 16;
  char* asd1 = (char*)As +  4096 + t * 16;
  char* asd2 = (char*)As +  8192 + t * 16;
  char* asd3 = (char*)As + 12288 + t * 16;
  char* bsd0 = (char*)Bs +     0 + t * 16;
  char* bsd1 = (char*)Bs +  4096 + t * 16;
  char* bsd2 = (char*)Bs +  8192 + t * 16;
  char* bsd3 = (char*)Bs + 12288 + t * 16;

  const int tq = lane & 15, qd = lane >> 4;

  f32x4 acc[4][4];
  #pragma unroll
  for (int i = 0; i < 4; ++i)
    #pragma unroll
    for (int j = 0; j < 4; ++j)
      acc[i][j] = f32x4{0.f, 0.f, 0.f, 0.f};

  const int kIters = K >> 6;
  for (int kt = 0; kt < kIters; ++kt) {
    __syncthreads();
    gl_lds16(ap0, asd0); gl_lds16(ap1, asd1);
    gl_lds16(ap2, asd2); gl_lds16(ap3, asd3);
    gl_lds16(bp0, bsd0); gl_lds16(bp1, bsd1);
    gl_lds16(bp2, bsd2); gl_lds16(bp3, bsd3);
    ap0 += 64; ap1 += 64; ap2 += 64; ap3 += 64;
    bp0 += 64; bp1 += 64; bp2 += 64; bp3 += 64;
    __builtin_amdgcn_s_waitcnt(0x0f70);    // vmcnt(0)
    __syncthreads();

    #pragma unroll
    for (int kk = 0; kk < 2; ++kk) {
      bf16x8 af[4], bfr[4];
      #pragma unroll
      for (int i = 0; i < 4; ++i) {
        const int R = wm * 64 + i * 16 + tq;
        const int slot = (kk * 4 + qd) ^ (R & 7);
        af[i] = *(const bf16x8*)(As + R * 64 + slot * 8);
      }
      #pragma unroll
      for (int j = 0; j < 4; ++j) {
        const int R = wn * 64 + j * 16 + tq;
        const int slot = (kk * 4 + qd) ^ (R & 7);
        bfr[j] = *(const bf16x8*)(Bs + R * 64 + slot * 8);
      }
      #pragma unroll
      for (int i = 0; i < 4; ++i)
        #pragma unroll
        for (int j = 0; j < 4; ++j)
          acc[i][j] = __builtin_amdgcn_mfma_f32_16x16x32_bf16(af[i], bfr[j], acc[i][j], 0, 0, 0);
    }
  }

  if (!F32OUT && Vt != nullptr && gh >= 16) {
    // V-head: write transposed bf16 -> Vt[(gb*8+gh-16)][dv=col][l=row]
    unsigned short* Vb = Vt + (size_t)(gb * 8 + (gh - 16)) * 131072;
    #pragma unroll
    for (int i = 0; i < 4; ++i) {
      const int row = m0 + wm * 64 + i * 16 + qd * 4;   // l (multiple of 4)
      #pragma unroll
      for (int j = 0; j < 4; ++j) {
        const int col = n0 + wn * 64 + j * 16 + tq;     // dv
        ushort4 o;
        o.x = f2bf(acc[i][j][0] * scale);
        o.y = f2bf(acc[i][j][1] * scale);
        o.z = f2bf(acc[i][j][2] * scale);
        o.w = f2bf(acc[i][j][3] * scale);
        *(ushort4*)(Vb + (size_t)col * 1024 + row) = o;
      }
    }
    return;
  }

  const size_t cOff = (size_t)z * sCl + (size_t)gb * sCb + (size_t)gh * sCh;
  #pragma unroll
  for (int i = 0; i < 4; ++i) {
    const int row = m0 + wm * 64 + i * 16 + qd * 4;   // C/D: row=(lane>>4)*4+reg
    #pragma unroll
    for (int j = 0; j < 4; ++j) {
      const int col = n0 + wn * 64 + j * 16 + tq;     // C/D: col=lane&15
      if constexpr (F32OUT) {
        float* C = (float*)Cv + cOff;
        #pragma unroll
        for (int rr = 0; rr < 4; ++rr)
          C[(size_t)(row + rr) * ldC + col] = acc[i][j][rr] * scale;
      } else {
        unsigned short* C = (unsigned short*)Cv + cOff;
        #pragma unroll
        for (int rr = 0; rr < 4; ++rr)
          C[(size_t)(row + rr) * ldC + col] = f2bf(acc[i][j][rr] * scale);
      }
    }
  }
}

// -------- pass 1: QK^T + exp + query-axis column sums, NO LDS staging ------
// 1024 blocks (bh x 16 q-strips of 64). Q/K fragments load DIRECTLY from
// global (L1/L2/L3-resident; per-tile working set 16 KB fits L1). No barriers
// in the k-loop: waves free-run. csacc slots each written once; one atomic
// pass at the end.
__global__ __launch_bounds__(256, 4) void scores_colsum(
    const unsigned short* __restrict__ QKV, float* __restrict__ colsum,
    const float* __restrict__ mask)
{
  __shared__ float csacc[2][1024];        // 8 KB per-wm partials
  const int bid = blockIdx.x;             // 1024; XCD chunk = 8 bh (qx fastest)
  const int w = ((bid & 7) << 7) | (bid >> 3);
  const int g = w >> 4, qx = w & 15;
  const int b = g >> 3, h = g & 7;
  const unsigned short* Qg = QKV + (size_t)b * 3145728 + (size_t)h * 131072
                                 + (size_t)qx * 8192;
  const unsigned short* Kg = QKV + (size_t)b * 3145728 + (size_t)(8 + h) * 131072;

  const int t = threadIdx.x;
  const int lane = t & 63, wave = t >> 6;
  const int wm = wave >> 1, wn = wave & 1;
  const int tq = lane & 15, qd = lane >> 4;

  // Q fragments direct: q = wm*32+i*16+tq, d-octet = kk*4+qd
  bf16x8 qf[2][4];
  #pragma unroll
  for (int i = 0; i < 2; ++i) {
    const int q = wm * 32 + i * 16 + tq;
    #pragma unroll
    for (int kk = 0; kk < 4; ++kk)
      qf[i][kk] = *(const bf16x8*)(Qg + (size_t)q * 128 + (kk * 4 + qd) * 8);
  }

  const float scl = 0.08838834764831845f;  // 1/sqrt(128)
  float aq[2][4];
  {
    const float* mrow = mask + (size_t)b * 1024 + qx * 64;
    #pragma unroll
    for (int i = 0; i < 2; ++i) {
      const float4 m4 = *(const float4*)(mrow + wm * 32 + i * 16 + qd * 4);
      aq[i][0] = (1.f - m4.x) * MASK_NEG - 20.f;
      aq[i][1] = (1.f - m4.y) * MASK_NEG - 20.f;
      aq[i][2] = (1.f - m4.z) * MASK_NEG - 20.f;
      aq[i][3] = (1.f - m4.w) * MASK_NEG - 20.f;
    }
  }

  for (int kt = 0; kt < 16; ++kt) {
    f32x4 acc_s[2][2];
    #pragma unroll
    for (int i = 0; i < 2; ++i)
      #pragma unroll
      for (int j = 0; j < 2; ++j)
        acc_s[i][j] = f32x4{0.f, 0.f, 0.f, 0.f};
    #pragma unroll
    for (int kk = 0; kk < 4; ++kk) {
      bf16x8 kf[2];
      #pragma unroll
      for (int j = 0; j < 2; ++j)
        kf[j] = *(const bf16x8*)(Kg + (size_t)(kt * 64 + wn * 32 + j * 16 + tq) * 128
                                     + (kk * 4 + qd) * 8);
      #pragma unroll
      for (int i = 0; i < 2; ++i)
        #pragma unroll
        for (int j = 0; j < 2; ++j)
          acc_s[i][j] = __builtin_amdgcn_mfma_f32_16x16x32_bf16(qf[i][kk], kf[j], acc_s[i][j], 0, 0, 0);
    }

    float cp0 = 0.f, cp1 = 0.f;
    #pragma unroll
    for (int i = 0; i < 2; ++i)
      #pragma unroll
      for (int rr = 0; rr < 4; ++rr) {
        cp0 += __expf(acc_s[i][0][rr] * scl + aq[i][rr]);
        cp1 += __expf(acc_s[i][1][rr] * scl + aq[i][rr]);
      }
    cp0 += __shfl_xor(cp0, 16, 64); cp0 += __shfl_xor(cp0, 32, 64);
    cp1 += __shfl_xor(cp1, 16, 64); cp1 += __shfl_xor(cp1, 32, 64);
    if (qd == 0) {                       // each entry written exactly once
      csacc[wm][kt * 64 + wn * 32 + tq] = cp0;
      csacc[wm][kt * 64 + wn * 32 + 16 + tq] = cp1;
    }
  }

  __syncthreads();
  float* cs = colsum + (size_t)g * 1024;
  #pragma unroll
  for (int r = 0; r < 4; ++r) {
    const int idx = r * 256 + t;
    atomicAdd(&cs[idx], csacc[0][idx] + csacc[1][idx]);
  }
}

// -------- pass 2: fused scores-recompute + normalization + P*V' ------------
// 1024 blocks (bh x 16 q-strips of 64). Q/K/V fragments DIRECT from global
// (no LDS staging, no vmcnt at barriers). LDS = only the 8 KB P buffer; two
// raw s_barriers/tile order the P write/read (lgkm only). V-frags issued
// before exp so their latency hides under QK^T+exp (T14).
__global__ __launch_bounds__(256, 3) void attn_pv_fused(
    const unsigned short* __restrict__ QKV, const unsigned short* __restrict__ Vp,
    unsigned short* __restrict__ Hp, const float* __restrict__ mask,
    const float* __restrict__ colsum)
{
  __shared__ unsigned short Ps[4096];     // [64 q][64 k] sw8, 8 KB

  const int bid = blockIdx.x;             // 1024; XCD chunk = 8 bh (qx fastest)
  const int w = ((bid & 7) << 7) | (bid >> 3);
  const int g = w >> 4, qx = w & 15;
  const int b = g >> 3, h = g & 7;
  const unsigned short* Qg = QKV + (size_t)b * 3145728 + (size_t)h * 131072
                                 + (size_t)qx * 8192;
  const unsigned short* Kg = QKV + (size_t)b * 3145728 + (size_t)(8 + h) * 131072;
  const unsigned short* Vg = Vp + (size_t)g * 131072;

  const int t = threadIdx.x;
  const int lane = t & 63, wave = t >> 6;
  const int wm = wave >> 1, wn = wave & 1;
  const int tq = lane & 15, qd = lane >> 4;

  // Q fragments direct
  bf16x8 qf[2][4];
  #pragma unroll
  for (int i = 0; i < 2; ++i) {
    const int q = wm * 32 + i * 16 + tq;
    #pragma unroll
    for (int kk = 0; kk < 4; ++kk)
      qf[i][kk] = *(const bf16x8*)(Qg + (size_t)q * 128 + (kk * 4 + qd) * 8);
  }

  f32x4 acc_h[2][4];
  #pragma unroll
  for (int i = 0; i < 2; ++i)
    #pragma unroll
    for (int j = 0; j < 4; ++j)
      acc_h[i][j] = f32x4{0.f, 0.f, 0.f, 0.f};

  const float scl = 0.08838834764831845f;  // 1/sqrt(128)
  float aq[2][4];
  {
    const float* mrow = mask + (size_t)b * 1024 + qx * 64;
    #pragma unroll
    for (int i = 0; i < 2; ++i) {
      const float4 m4 = *(const float4*)(mrow + wm * 32 + i * 16 + qd * 4);
      aq[i][0] = (1.f - m4.x) * MASK_NEG - 20.f;
      aq[i][1] = (1.f - m4.y) * MASK_NEG - 20.f;
      aq[i][2] = (1.f - m4.z) * MASK_NEG - 20.f;
      aq[i][3] = (1.f - m4.w) * MASK_NEG - 20.f;
    }
  }
  const float* cs = colsum + (size_t)g * 1024;

  for (int kt = 0; kt < 16; ++kt) {
    __builtin_amdgcn_s_barrier();          // prev tile's P reads done
    __builtin_amdgcn_sched_barrier(0);

    // V fragments issued EARLY (consumed after next barrier) — T14
    bf16x8 vf[2][4];
    #pragma unroll
    for (int k2 = 0; k2 < 2; ++k2)
      #pragma unroll
      for (int j = 0; j < 4; ++j)
        vf[k2][j] = *(const bf16x8*)(Vg + (size_t)(wn * 64 + j * 16 + tq) * 1024
                                         + kt * 64 + (k2 * 4 + qd) * 8);

    // ---- S = Q * K^T : per-wave quadrant [32 q][32 k], K-frags direct ----
    f32x4 acc_s[2][2];
    #pragma unroll
    for (int i = 0; i < 2; ++i)
      #pragma unroll
      for (int j = 0; j < 2; ++j)
        acc_s[i][j] = f32x4{0.f, 0.f, 0.f, 0.f};
    __builtin_amdgcn_s_setprio(1);
    #pragma unroll
    for (int kk = 0; kk < 4; ++kk) {
      bf16x8 kf[2];
      #pragma unroll
      for (int j = 0; j < 2; ++j)
        kf[j] = *(const bf16x8*)(Kg + (size_t)(kt * 64 + wn * 32 + j * 16 + tq) * 128
                                     + (kk * 4 + qd) * 8);
      #pragma unroll
      for (int i = 0; i < 2; ++i)
        #pragma unroll
        for (int j = 0; j < 2; ++j)
          acc_s[i][j] = __builtin_amdgcn_mfma_f32_16x16x32_bf16(qf[i][kk], kf[j], acc_s[i][j], 0, 0, 0);
    }
    __builtin_amdgcn_s_setprio(0);

    // ---- P = exp(S') / colsum[k] -> LDS (bf16, 8-slot swizzle) ----
    const float rcs0 = 1.0f / cs[kt * 64 + wn * 32 + tq];
    const float rcs1 = 1.0f / cs[kt * 64 + wn * 32 + 16 + tq];
    #pragma unroll
    for (int i = 0; i < 2; ++i) {
      const int q0 = wm * 32 + i * 16 + qd * 4;
      #pragma unroll
      for (int rr = 0; rr < 4; ++rr) {
        const int q = q0 + rr;
        #pragma unroll
        for (int j = 0; j < 2; ++j) {
          const int kl = wn * 32 + j * 16 + tq;
          const float e = __expf(acc_s[i][j][rr] * scl + aq[i][rr]) * (j ? rcs1 : rcs0);
          Ps[q * 64 + (((kl >> 3) ^ (q & 7)) * 8) + (kl & 7)] = f2bf(e);
        }
      }
    }
    asm volatile("s_waitcnt lgkmcnt(0)" ::: "memory");
    __builtin_amdgcn_s_barrier();          // P visible to all
    __builtin_amdgcn_sched_barrier(0);

    // ---- H += P * V'^T : per-wave [32 q][64 dv], contraction 64 ----
    __builtin_amdgcn_s_setprio(1);
    #pragma unroll
    for (int k2 = 0; k2 < 2; ++k2) {
      const int o = k2 * 4 + qd;           // k-octet
      bf16x8 pf[2];
      #pragma unroll
      for (int i = 0; i < 2; ++i) {
        const int q = wm * 32 + i * 16 + tq;
        pf[i] = *(const bf16x8*)(Ps + q * 64 + ((o ^ (q & 7)) * 8));
      }
      #pragma unroll
      for (int i = 0; i < 2; ++i)
        #pragma unroll
        for (int j = 0; j < 4; ++j)
          acc_h[i][j] = __builtin_amdgcn_mfma_f32_16x16x32_bf16(pf[i], vf[k2][j], acc_h[i][j], 0, 0, 0);
    }
    __builtin_amdgcn_s_setprio(0);
  }

  // ---- epilogue: Hp[b][qx*64 + q][h*128 + dv] ----
  unsigned short* Hb = Hp + (size_t)b * 1048576 + (size_t)qx * 65536 + h * 128;
  #pragma unroll
  for (int i = 0; i < 2; ++i) {
    const int q0 = wm * 32 + i * 16 + qd * 4;
    #pragma unroll
    for (int j = 0; j < 4; ++j) {
      const int dv = wn * 64 + j * 16 + tq;
      #pragma unroll
      for (int rr = 0; rr < 4; ++rr)
        Hb[(size_t)(q0 + rr) * 1024 + dv] = f2bf(acc_h[i][j][rr]);
    }
  }
}

extern "C" void kernel_launch(void* const* d_in, const int* in_sizes, int n_in,
                              void* d_out, int out_size, void* d_ws, size_t ws_size,
                              hipStream_t stream) {
  const float* x    = (const float*)d_in[0];   // [8,1024,1024]  (B,D,L)
  const float* mask = (const float*)d_in[1];   // [8,1024]
  const float* Wq   = (const float*)d_in[2];   // [8,1024,128]
  const float* Wk   = (const float*)d_in[3];
  const float* Wv   = (const float*)d_in[4];
  const float* Wo   = (const float*)d_in[5];   // [1024,1024]
  float* out = (float*)d_out;                  // [8,1024,1024]  (B,D,L)

  char* p = (char*)d_ws;
  unsigned short* xt    = (unsigned short*)p; p += 16777216;  // [b][l][d] bf16
  unsigned short* WqkvT = (unsigned short*)p; p += 6291456;   // [24 heads][128][1024]
  unsigned short* Wot   = (unsigned short*)p; p += 2097152;   // [j][i]
  unsigned short* QKV   = (unsigned short*)p; p += 50331648;  // [b][24h][l][128] (V region unused)
  unsigned short* Vp    = (unsigned short*)p; p += 16777216;  // [b][h][dv][l] (unnormalized V^T)
  unsigned short* Hp    = (unsigned short*)p; p += 16777216;  // [b][l][h*128+dv]
  float* colsum = (float*)p; p += 262144;                     // [64][1024] fp32

  hipMemsetAsync(colsum, 0, 262144, stream);

  // prologue: transposes
  transpose_x_wo<<<dim3(16, 16, 9), 256, 0, stream>>>(x, Wo, xt, Wot);
  transpose_w24<<<dim3(2, 16, 24), 256, 0, stream>>>(Wq, Wk, Wv, WqkvT);

  // QKV[b][gh][l][dk] = xt[b] * WqkvT[gh]^T ; V-heads (gh>=16) written
  // transposed directly into Vp.
  gemm_tn<false><<<dim3(1, 8, 192), 256, 0, stream>>>(
      xt, WqkvT, (void*)QKV, 1024, 1024, 1024, 128, 1.f,
      0L, 1048576L, 0L,  0L, 0L, 131072L,  0L, 3145728L, 131072L, 0, 24, Vp);

  // pass 1: colsum (direct-frag loads, barrier-free k-loop)
  scores_colsum<<<dim3(1024, 1, 1), 256, 0, stream>>>(QKV, colsum, mask);

  // pass 2: fused scores-recompute + normalization + PV (direct-frag loads)
  attn_pv_fused<<<dim3(1024, 1, 1), 256, 0, stream>>>(QKV, Vp, Hp, mask, colsum);

  // out[b][j][l] = Wot[j,:] . H[b][l,:]
  gemm_tn<true><<<dim3(8, 8, 8), 256, 0, stream>>>(
      Wot, Hp, (void*)out, 1024, 1024, 1024, 1024, 1.f,
      0L, 0L, 0L,  0L, 1048576L, 0L,  0L, 1048576L, 0L, 0, 1, nullptr);
}

// Round 7
// 267.843 us; speedup vs baseline: 1.6653x; 1.6653x over previous
//
#include <hip/hip_runtime.h>

typedef short bf16x8 __attribute__((ext_vector_type(8)));
typedef float f32x4 __attribute__((ext_vector_type(4)));
typedef unsigned short u16x8 __attribute__((ext_vector_type(8)));

#define MASK_NEG (-1e30f)

__device__ __forceinline__ unsigned short f2bf(float f) {
  union { float f; unsigned u; } v; v.f = f;
  unsigned r = v.u + 0x7fffu + ((v.u >> 16) & 1u);
  return (unsigned short)(r >> 16);
}

__device__ __forceinline__ float bf2f(unsigned short u) {
  union { unsigned u; float f; } v; v.u = ((unsigned)u) << 16;
  return v.f;
}

__device__ __forceinline__ void gl_lds16(const void* g, void* l) {
  __builtin_amdgcn_global_load_lds(
      (__attribute__((address_space(1))) void*)(void*)g,
      (__attribute__((address_space(3))) void*)l, 16, 0, 0);
}

// -------- shared transpose body: dst[c][r] = bf16(src[r][c]), 64x64 tile ----
__device__ __forceinline__ void transpose_tile(
    const float* __restrict__ s, unsigned short* __restrict__ d,
    int R, int C, int x0, int y0, int t, float tile[64][65]) {
  {
    const int r = t >> 4, c4 = (t & 15) * 4;
    for (int it = 0; it < 4; ++it) {
      const int rr = r + it * 16;
      const float4 v = *(const float4*)(s + (size_t)(y0 + rr) * C + x0 + c4);
      tile[rr][c4 + 0] = v.x; tile[rr][c4 + 1] = v.y;
      tile[rr][c4 + 2] = v.z; tile[rr][c4 + 3] = v.w;
    }
  }
  __syncthreads();
  {
    const int cc = t >> 4, r4 = (t & 15) * 4;
    for (int it = 0; it < 4; ++it) {
      const int c = cc + it * 16;
      ushort4 o;
      o.x = f2bf(tile[r4 + 0][c]); o.y = f2bf(tile[r4 + 1][c]);
      o.z = f2bf(tile[r4 + 2][c]); o.w = f2bf(tile[r4 + 3][c]);
      *(ushort4*)(d + (size_t)(x0 + c) * R + y0 + r4) = o;
    }
  }
}

// -------- transpose x (8 batches) + Wo, all 1024x1024, one dispatch --------
__global__ __launch_bounds__(256) void transpose_x_wo(
    const float* __restrict__ x, const float* __restrict__ Wo,
    unsigned short* __restrict__ xt, unsigned short* __restrict__ Wot) {
  __shared__ float tile[64][65];
  const int z = blockIdx.z;   // 0..7: x batch, 8: Wo
  const float* s = (z < 8) ? (x + (size_t)z * 1048576) : Wo;
  unsigned short* d = (z < 8) ? (xt + (size_t)z * 1048576) : Wot;
  transpose_tile(s, d, 1024, 1024, blockIdx.x * 64, blockIdx.y * 64,
                 threadIdx.x, tile);
}

// -------- transpose all 24 per-head W matrices (1024x128) in one dispatch ---
__global__ __launch_bounds__(256) void transpose_w24(
    const float* __restrict__ Wq, const float* __restrict__ Wk,
    const float* __restrict__ Wv, unsigned short* __restrict__ WqkvT) {
  __shared__ float tile[64][65];
  const int z = blockIdx.z;   // 0..23
  const int sel = z >> 3, h = z & 7;
  const float* base = (sel == 0) ? Wq : (sel == 1) ? Wk : Wv;
  const float* s = base + (size_t)h * 131072;
  unsigned short* d = WqkvT + (size_t)z * 131072;
  transpose_tile(s, d, 1024, 128, blockIdx.x * 64, blockIdx.y * 64,
                 threadIdx.x, tile);
}

// -------- generic bf16 MFMA GEMM, BK=64 (m97 staging) -----------------------
// C[M,N] = scale * A[M,K] * B[N,K]^T ; A,B K-contiguous; K % 64 == 0.
// Chunked XCD swizzle when nwg % 8 == 0 (T1). If Vt != null and gh >= 16,
// the block's output is written TRANSPOSED (bf16) into Vt[(gb*8+gh-16)][col][row]
// instead of C (used by the QKV GEMM to produce V' = V^T directly).
template<bool F32OUT>
__global__ __launch_bounds__(256) void gemm_tn(
    const unsigned short* __restrict__ A, const unsigned short* __restrict__ B,
    void* __restrict__ Cv,
    int K, int ldA, int ldB, int ldC, float scale,
    long sAl, long sAb, long sAh,
    long sBl, long sBb, long sBh,
    long sCl, long sCb, long sCh,
    int zbase, int zdiv, unsigned short* __restrict__ Vt)
{
  __shared__ unsigned short As[128 * 64];   // [128 rows][64 k], chunk-swizzled
  __shared__ unsigned short Bs[128 * 64];
  int bx, by, bz;
  {
    const int nx = gridDim.x, ny = gridDim.y;
    const int nwg = nx * ny * gridDim.z;
    int flat = blockIdx.x + nx * (blockIdx.y + ny * blockIdx.z);
    if ((nwg & 7) == 0) flat = (flat & 7) * (nwg >> 3) + (flat >> 3);
    bx = flat % nx; flat /= nx;
    by = flat % ny; bz = flat / ny;
  }
  const int z = bz;
  const int g = zbase + z;
  const int gb = g / zdiv, gh = g % zdiv;
  const unsigned short* Ab = A + (size_t)z * sAl + (size_t)gb * sAb + (size_t)gh * sAh;
  const unsigned short* Bb = B + (size_t)z * sBl + (size_t)gb * sBb + (size_t)gh * sBh;
  const int m0 = by * 128, n0 = bx * 128;
  const int t = threadIdx.x;
  const int lane = t & 63;
  const int wave = t >> 6;
  const int wm = wave >> 1, wn = wave & 1;

  const int sr2 = t >> 3;          // 0..31
  const int ss8 = t & 7;
  const int sq8 = ss8 ^ (sr2 & 7);

  const unsigned short* ap0 = Ab + (size_t)(m0 +  0 + sr2) * ldA + sq8 * 8;
  const unsigned short* ap1 = Ab + (size_t)(m0 + 32 + sr2) * ldA + sq8 * 8;
  const unsigned short* ap2 = Ab + (size_t)(m0 + 64 + sr2) * ldA + sq8 * 8;
  const unsigned short* ap3 = Ab + (size_t)(m0 + 96 + sr2) * ldA + sq8 * 8;
  const unsigned short* bp0 = Bb + (size_t)(n0 +  0 + sr2) * ldB + sq8 * 8;
  const unsigned short* bp1 = Bb + (size_t)(n0 + 32 + sr2) * ldB + sq8 * 8;
  const unsigned short* bp2 = Bb + (size_t)(n0 + 64 + sr2) * ldB + sq8 * 8;
  const unsigned short* bp3 = Bb + (size_t)(n0 + 96 + sr2) * ldB + sq8 * 8;

  char* asd0 = (char*)As +     0 + t * 16;
  char* asd1 = (char*)As +  4096 + t * 16;
  char* asd2 = (char*)As +  8192 + t * 16;
  char* asd3 = (char*)As + 12288 + t * 16;
  char* bsd0 = (char*)Bs +     0 + t * 16;
  char* bsd1 = (char*)Bs +  4096 + t * 16;
  char* bsd2 = (char*)Bs +  8192 + t * 16;
  char* bsd3 = (char*)Bs + 12288 + t * 16;

  const int tq = lane & 15, qd = lane >> 4;

  f32x4 acc[4][4];
  #pragma unroll
  for (int i = 0; i < 4; ++i)
    #pragma unroll
    for (int j = 0; j < 4; ++j)
      acc[i][j] = f32x4{0.f, 0.f, 0.f, 0.f};

  const int kIters = K >> 6;
  for (int kt = 0; kt < kIters; ++kt) {
    __syncthreads();
    gl_lds16(ap0, asd0); gl_lds16(ap1, asd1);
    gl_lds16(ap2, asd2); gl_lds16(ap3, asd3);
    gl_lds16(bp0, bsd0); gl_lds16(bp1, bsd1);
    gl_lds16(bp2, bsd2); gl_lds16(bp3, bsd3);
    ap0 += 64; ap1 += 64; ap2 += 64; ap3 += 64;
    bp0 += 64; bp1 += 64; bp2 += 64; bp3 += 64;
    __builtin_amdgcn_s_waitcnt(0x0f70);    // vmcnt(0)
    __syncthreads();

    #pragma unroll
    for (int kk = 0; kk < 2; ++kk) {
      bf16x8 af[4], bfr[4];
      #pragma unroll
      for (int i = 0; i < 4; ++i) {
        const int R = wm * 64 + i * 16 + tq;
        const int slot = (kk * 4 + qd) ^ (R & 7);
        af[i] = *(const bf16x8*)(As + R * 64 + slot * 8);
      }
      #pragma unroll
      for (int j = 0; j < 4; ++j) {
        const int R = wn * 64 + j * 16 + tq;
        const int slot = (kk * 4 + qd) ^ (R & 7);
        bfr[j] = *(const bf16x8*)(Bs + R * 64 + slot * 8);
      }
      #pragma unroll
      for (int i = 0; i < 4; ++i)
        #pragma unroll
        for (int j = 0; j < 4; ++j)
          acc[i][j] = __builtin_amdgcn_mfma_f32_16x16x32_bf16(af[i], bfr[j], acc[i][j], 0, 0, 0);
    }
  }

  if (!F32OUT && Vt != nullptr && gh >= 16) {
    // V-head: write transposed bf16 -> Vt[(gb*8+gh-16)][dv=col][l=row]
    unsigned short* Vb = Vt + (size_t)(gb * 8 + (gh - 16)) * 131072;
    #pragma unroll
    for (int i = 0; i < 4; ++i) {
      const int row = m0 + wm * 64 + i * 16 + qd * 4;   // l (multiple of 4)
      #pragma unroll
      for (int j = 0; j < 4; ++j) {
        const int col = n0 + wn * 64 + j * 16 + tq;     // dv
        ushort4 o;
        o.x = f2bf(acc[i][j][0] * scale);
        o.y = f2bf(acc[i][j][1] * scale);
        o.z = f2bf(acc[i][j][2] * scale);
        o.w = f2bf(acc[i][j][3] * scale);
        *(ushort4*)(Vb + (size_t)col * 1024 + row) = o;
      }
    }
    return;
  }

  const size_t cOff = (size_t)z * sCl + (size_t)gb * sCb + (size_t)gh * sCh;
  #pragma unroll
  for (int i = 0; i < 4; ++i) {
    const int row = m0 + wm * 64 + i * 16 + qd * 4;   // C/D: row=(lane>>4)*4+reg
    #pragma unroll
    for (int j = 0; j < 4; ++j) {
      const int col = n0 + wn * 64 + j * 16 + tq;     // C/D: col=lane&15
      if constexpr (F32OUT) {
        float* C = (float*)Cv + cOff;
        #pragma unroll
        for (int rr = 0; rr < 4; ++rr)
          C[(size_t)(row + rr) * ldC + col] = acc[i][j][rr] * scale;
      } else {
        unsigned short* C = (unsigned short*)Cv + cOff;
        #pragma unroll
        for (int rr = 0; rr < 4; ++rr)
          C[(size_t)(row + rr) * ldC + col] = f2bf(acc[i][j][rr] * scale);
      }
    }
  }
}

// -------- pass 1: strip-mined QK^T + exp + query-axis column sums ----------
// One block per (bh, 128-q strip). Q staged once -> VGPR frags; K tiles
// (64x128) double-buffered. RAW s_barrier + counted vmcnt: prefetch stays in
// flight across barriers. LDS colsum partials; one atomic pass at the end.
// NO non-prefetch VMEM inside the loop (keeps vmcnt counts honest).
__global__ __launch_bounds__(256, 2) void scores_colsum(
    const unsigned short* __restrict__ QKV, float* __restrict__ colsum,
    const float* __restrict__ mask)
{
  __shared__ unsigned short lds[24576];   // 48 KB: Qs 32 KB | K slot0 16 KB
  __shared__ float csacc[2][1024];        // per-wm colsum partials (8 KB)
  unsigned short* Qs = lds;               // [128][128] sw16 (prologue only)
  // K dbuf: slot0 = lds+16384 elems, slot1 = lds+0 (overlays dead Qs)

  const int bid = blockIdx.x;             // 512 blocks; XCD chunk = 8 bh
  const int w = ((bid & 7) << 6) | (bid >> 3);
  const int g = w >> 3, qx = w & 7;
  const int b = g >> 3, h = g & 7;
  const unsigned short* Qg = QKV + (size_t)b * 3145728 + (size_t)h * 131072
                                 + (size_t)qx * 16384;
  const unsigned short* Kg = QKV + (size_t)b * 3145728 + (size_t)(8 + h) * 131072;

  const int t = threadIdx.x;
  const int lane = t & 63, wave = t >> 6;
  const int wm = wave >> 1, wn = wave & 1;
  const int tq = lane & 15, qd = lane >> 4;

  // prologue: stage Q (8 chunks) + K-tile 0 (4 chunks)
  #pragma unroll
  for (int it = 0; it < 8; ++it) {
    const int c = it * 256 + t;
    const int row = c >> 4;
    const int src = (c ^ (c >> 4)) & 15;
    gl_lds16(Qg + (size_t)row * 128 + src * 8, (char*)Qs + c * 16);
  }
  #pragma unroll
  for (int it = 0; it < 4; ++it) {
    const int c = it * 256 + t;
    const int row = c >> 4;
    const int src = (c ^ (c >> 4)) & 15;
    gl_lds16(Kg + (size_t)row * 128 + src * 8, (char*)(lds + 16384) + c * 16);
  }
  __builtin_amdgcn_s_waitcnt(0x0f70);    // vmcnt(0)
  __syncthreads();

  bf16x8 qf[4][4];
  #pragma unroll
  for (int i = 0; i < 4; ++i) {
    const int R = wm * 64 + i * 16 + tq;
    #pragma unroll
    for (int kk = 0; kk < 4; ++kk)
      qf[i][kk] = *(const bf16x8*)(Qs + R * 128 + (((kk * 4 + qd) ^ (R & 15)) * 8));
  }
  __syncthreads();   // Qs dead; region becomes K slot1

  const float scl = 0.08838834764831845f;  // 1/sqrt(128)
  float aq[4][4];
  {
    const float* mrow = mask + (size_t)b * 1024 + qx * 128;
    #pragma unroll
    for (int i = 0; i < 4; ++i) {
      const float4 m4 = *(const float4*)(mrow + wm * 64 + i * 16 + qd * 4);
      aq[i][0] = (1.f - m4.x) * MASK_NEG - 20.f;
      aq[i][1] = (1.f - m4.y) * MASK_NEG - 20.f;
      aq[i][2] = (1.f - m4.z) * MASK_NEG - 20.f;
      aq[i][3] = (1.f - m4.w) * MASK_NEG - 20.f;
    }
  }

  for (int kt = 0; kt < 16; ++kt) {
    __builtin_amdgcn_s_barrier();        // B1: target slot's readers done
    __builtin_amdgcn_sched_barrier(0);
    if (kt < 15) {
      unsigned short* Kn = ((kt + 1) & 1) ? lds : (lds + 16384);
      const unsigned short* Kgn = Kg + (size_t)(kt + 1) * 8192;
      #pragma unroll
      for (int it = 0; it < 4; ++it) {
        const int c = it * 256 + t;
        const int row = c >> 4;
        const int src = (c ^ (c >> 4)) & 15;
        gl_lds16(Kgn + (size_t)row * 128 + src * 8, (char*)Kn + c * 16);
      }
      asm volatile("s_waitcnt vmcnt(4)" ::: "memory");   // kt's K landed
    } else {
      asm volatile("s_waitcnt vmcnt(0)" ::: "memory");
    }
    __builtin_amdgcn_s_barrier();        // B2: tile kt visible to all
    __builtin_amdgcn_sched_barrier(0);

    const unsigned short* Kc = (kt & 1) ? lds : (lds + 16384);
    f32x4 acc_s[4][2];
    #pragma unroll
    for (int i = 0; i < 4; ++i)
      #pragma unroll
      for (int j = 0; j < 2; ++j)
        acc_s[i][j] = f32x4{0.f, 0.f, 0.f, 0.f};
    __builtin_amdgcn_s_setprio(1);
    #pragma unroll
    for (int kk = 0; kk < 4; ++kk) {
      bf16x8 kf[2];
      #pragma unroll
      for (int j = 0; j < 2; ++j) {
        const int R = wn * 32 + j * 16 + tq;
        kf[j] = *(const bf16x8*)(Kc + R * 128 + (((kk * 4 + qd) ^ (R & 15)) * 8));
      }
      #pragma unroll
      for (int i = 0; i < 4; ++i)
        #pragma unroll
        for (int j = 0; j < 2; ++j)
          acc_s[i][j] = __builtin_amdgcn_mfma_f32_16x16x32_bf16(qf[i][kk], kf[j], acc_s[i][j], 0, 0, 0);
    }
    __builtin_amdgcn_s_setprio(0);

    float cp0 = 0.f, cp1 = 0.f;
    #pragma unroll
    for (int i = 0; i < 4; ++i)
      #pragma unroll
      for (int rr = 0; rr < 4; ++rr) {
        cp0 += __expf(acc_s[i][0][rr] * scl + aq[i][rr]);
        cp1 += __expf(acc_s[i][1][rr] * scl + aq[i][rr]);
      }
    cp0 += __shfl_xor(cp0, 16, 64); cp0 += __shfl_xor(cp0, 32, 64);
    cp1 += __shfl_xor(cp1, 16, 64); cp1 += __shfl_xor(cp1, 32, 64);
    if (qd == 0) {                       // each entry written exactly once
      csacc[wm][kt * 64 + wn * 32 + tq] = cp0;
      csacc[wm][kt * 64 + wn * 32 + 16 + tq] = cp1;
    }
  }

  __syncthreads();                       // csacc complete (full drain, once)
  float* cs = colsum + (size_t)g * 1024;
  #pragma unroll
  for (int r = 0; r < 4; ++r) {
    const int idx = r * 256 + t;
    atomicAdd(&cs[idx], csacc[0][idx] + csacc[1][idx]);
  }
}

// -------- vnorm: Vpn[b][16+h][dv][l] = Vpu[g][dv][l] / colsum[g][l] --------
// Writes the normalized V' into the QKV buffer's (otherwise unused) V region,
// so pass 2's k-loop needs ZERO non-prefetch VMEM.
__global__ __launch_bounds__(256) void vnorm(
    const unsigned short* __restrict__ Vpu, unsigned short* __restrict__ QKV,
    const float* __restrict__ colsum)
{
  const int g = blockIdx.y;               // 0..63
  const int b = g >> 3, h = g & 7;
  const unsigned short* S = Vpu + (size_t)g * 131072;
  unsigned short* D = QKV + (size_t)b * 3145728 + (size_t)(16 + h) * 131072;
  const float* cs = colsum + (size_t)g * 1024;
  const int off = (blockIdx.x * 256 + threadIdx.x) * 8;   // 64 x-blocks
  const int l0 = off & 1023;
  const u16x8 v = *(const u16x8*)(S + off);
  const float4 c0 = *(const float4*)(cs + l0);
  const float4 c1 = *(const float4*)(cs + l0 + 4);
  u16x8 o;
  o[0] = f2bf(bf2f(v[0]) / c0.x); o[1] = f2bf(bf2f(v[1]) / c0.y);
  o[2] = f2bf(bf2f(v[2]) / c0.z); o[3] = f2bf(bf2f(v[3]) / c0.w);
  o[4] = f2bf(bf2f(v[4]) / c1.x); o[5] = f2bf(bf2f(v[5]) / c1.y);
  o[6] = f2bf(bf2f(v[6]) / c1.z); o[7] = f2bf(bf2f(v[7]) / c1.w);
  *(u16x8*)(D + off) = o;
}

// -------- pass 2: fused scores-recompute + P*V'n accumulation --------------
// K/V double-buffered; RAW s_barrier + counted vmcnt; the ONLY VMEM in the
// loop is the 8 prefetch global_load_lds, so vmcnt(12)/(8) are honest counts
// and the prefetch truly stays in flight across all three barriers.
__global__ __launch_bounds__(256, 2) void attn_pv_fused(
    const unsigned short* __restrict__ QKV,
    unsigned short* __restrict__ Hp, const float* __restrict__ mask)
{
  __shared__ unsigned short lds[40960];   // 80 KB (element offsets below)
  unsigned short* Ps = lds;               // [128][64] sw8, bytes 0..16K
  // K dbuf: slot0 = lds+16384 (bytes 32K..48K), slot1 = lds+8192 (16K..32K)
  // V dbuf: slot0 = lds+24576 (48K..64K),       slot1 = lds+32768 (64K..80K)
  // Qs prologue = lds[0..16384 elems) = bytes 0..32K (overlays Ps + K slot1)
  unsigned short* Qs = lds;

  const int bid = blockIdx.x;             // 512 blocks; XCD chunk = 8 bh
  const int w = ((bid & 7) << 6) | (bid >> 3);
  const int g = w >> 3, qx = w & 7;
  const int b = g >> 3, h = g & 7;
  const unsigned short* Qg = QKV + (size_t)b * 3145728 + (size_t)h * 131072
                                 + (size_t)qx * 16384;
  const unsigned short* Kg = QKV + (size_t)b * 3145728 + (size_t)(8 + h) * 131072;
  const unsigned short* Vg = QKV + (size_t)b * 3145728 + (size_t)(16 + h) * 131072;

  const int t = threadIdx.x;
  const int lane = t & 63, wave = t >> 6;
  const int wm = wave >> 1, wn = wave & 1;
  const int tq = lane & 15, qd = lane >> 4;

  // ---- prologue: stage Q + K0 + V0 ----
  #pragma unroll
  for (int it = 0; it < 8; ++it) {
    const int c = it * 256 + t;
    const int row = c >> 4;
    const int src = (c ^ (c >> 4)) & 15;
    gl_lds16(Qg + (size_t)row * 128 + src * 8, (char*)Qs + c * 16);
  }
  #pragma unroll
  for (int it = 0; it < 4; ++it) {
    const int c = it * 256 + t;
    const int row = c >> 4;
    const int src = (c ^ (c >> 4)) & 15;
    gl_lds16(Kg + (size_t)row * 128 + src * 8, (char*)(lds + 16384) + c * 16);
  }
  #pragma unroll
  for (int it = 0; it < 4; ++it) {
    const int c = it * 256 + t;
    const int row = c >> 3;
    const int src = (c ^ (c >> 3)) & 7;
    gl_lds16(Vg + (size_t)row * 1024 + src * 8, (char*)(lds + 24576) + c * 16);
  }
  __builtin_amdgcn_s_waitcnt(0x0f70);    // vmcnt(0)
  __syncthreads();

  bf16x8 qf[4][4];
  #pragma unroll
  for (int i = 0; i < 4; ++i) {
    const int R = wm * 64 + i * 16 + tq;
    #pragma unroll
    for (int kk = 0; kk < 4; ++kk)
      qf[i][kk] = *(const bf16x8*)(Qs + R * 128 + (((kk * 4 + qd) ^ (R & 15)) * 8));
  }
  __syncthreads();   // Qs dead; region becomes Ps + K slot1

  f32x4 acc_h[4][4];
  #pragma unroll
  for (int i = 0; i < 4; ++i)
    #pragma unroll
    for (int j = 0; j < 4; ++j)
      acc_h[i][j] = f32x4{0.f, 0.f, 0.f, 0.f};

  const float scl = 0.08838834764831845f;  // 1/sqrt(128)
  float aq[4][4];
  {
    const float* mrow = mask + (size_t)b * 1024 + qx * 128;
    #pragma unroll
    for (int i = 0; i < 4; ++i) {
      const float4 m4 = *(const float4*)(mrow + wm * 64 + i * 16 + qd * 4);
      aq[i][0] = (1.f - m4.x) * MASK_NEG - 20.f;
      aq[i][1] = (1.f - m4.y) * MASK_NEG - 20.f;
      aq[i][2] = (1.f - m4.z) * MASK_NEG - 20.f;
      aq[i][3] = (1.f - m4.w) * MASK_NEG - 20.f;
    }
  }

  for (int kt = 0; kt < 16; ++kt) {
    __builtin_amdgcn_s_barrier();        // B1: target bufs' readers done
    __builtin_amdgcn_sched_barrier(0);
    if (kt < 15) {
      unsigned short* Kn = ((kt + 1) & 1) ? (lds + 8192) : (lds + 16384);
      unsigned short* Vn = ((kt + 1) & 1) ? (lds + 32768) : (lds + 24576);
      const unsigned short* Kgn = Kg + (size_t)(kt + 1) * 8192;
      #pragma unroll
      for (int it = 0; it < 4; ++it) {
        const int c = it * 256 + t;
        const int row = c >> 4;
        const int src = (c ^ (c >> 4)) & 15;
        gl_lds16(Kgn + (size_t)row * 128 + src * 8, (char*)Kn + c * 16);
      }
      #pragma unroll
      for (int it = 0; it < 4; ++it) {
        const int c = it * 256 + t;
        const int row = c >> 3;
        const int src = (c ^ (c >> 3)) & 7;
        gl_lds16(Vg + (size_t)row * 1024 + (kt + 1) * 64 + src * 8, (char*)Vn + c * 16);
      }
      asm volatile("s_waitcnt vmcnt(12)" ::: "memory");   // kt's K landed
    } else {
      asm volatile("s_waitcnt vmcnt(4)" ::: "memory");    // K15 landed
    }
    __builtin_amdgcn_s_barrier();        // B2: K(kt) visible to all
    __builtin_amdgcn_sched_barrier(0);

    const unsigned short* Kc = (kt & 1) ? (lds + 8192) : (lds + 16384);
    const unsigned short* Vc = (kt & 1) ? (lds + 32768) : (lds + 24576);

    // ---- S = Q * K^T : per-wave quadrant [64 q][32 k] ----
    f32x4 acc_s[4][2];
    #pragma unroll
    for (int i = 0; i < 4; ++i)
      #pragma unroll
      for (int j = 0; j < 2; ++j)
        acc_s[i][j] = f32x4{0.f, 0.f, 0.f, 0.f};
    __builtin_amdgcn_s_setprio(1);
    #pragma unroll
    for (int kk = 0; kk < 4; ++kk) {
      bf16x8 kf[2];
      #pragma unroll
      for (int j = 0; j < 2; ++j) {
        const int R = wn * 32 + j * 16 + tq;
        kf[j] = *(const bf16x8*)(Kc + R * 128 + (((kk * 4 + qd) ^ (R & 15)) * 8));
      }
      #pragma unroll
      for (int i = 0; i < 4; ++i)
        #pragma unroll
        for (int j = 0; j < 2; ++j)
          acc_s[i][j] = __builtin_amdgcn_mfma_f32_16x16x32_bf16(qf[i][kk], kf[j], acc_s[i][j], 0, 0, 0);
    }
    __builtin_amdgcn_s_setprio(0);

    // ---- P = exp(S') -> LDS (bf16, 8-slot swizzle); V'n is pre-normalized --
    #pragma unroll
    for (int i = 0; i < 4; ++i) {
      const int q0 = wm * 64 + i * 16 + qd * 4;
      #pragma unroll
      for (int rr = 0; rr < 4; ++rr) {
        const int q = q0 + rr;
        #pragma unroll
        for (int j = 0; j < 2; ++j) {
          const int kl = wn * 32 + j * 16 + tq;
          const float e = __expf(acc_s[i][j][rr] * scl + aq[i][rr]);
          Ps[q * 64 + ((((kl >> 3) ^ (q & 7)) * 8) | (kl & 7))] = f2bf(e);
        }
      }
    }
    if (kt < 15)
      asm volatile("s_waitcnt vmcnt(8) lgkmcnt(0)" ::: "memory");  // V(kt)+P
    else
      asm volatile("s_waitcnt vmcnt(0) lgkmcnt(0)" ::: "memory");
    __builtin_amdgcn_s_barrier();        // B3: V(kt) + P visible
    __builtin_amdgcn_sched_barrier(0);

    // ---- H += P * V'^T : per-wave [64 q][64 dv], contraction 64 ----
    __builtin_amdgcn_s_setprio(1);
    #pragma unroll
    for (int k2 = 0; k2 < 2; ++k2) {
      bf16x8 pf[4], vf[4];
      #pragma unroll
      for (int i = 0; i < 4; ++i) {
        const int R = wm * 64 + i * 16 + tq;
        pf[i] = *(const bf16x8*)(Ps + R * 64 + (((k2 * 4 + qd) ^ (R & 7)) * 8));
      }
      #pragma unroll
      for (int j = 0; j < 4; ++j) {
        const int R = wn * 64 + j * 16 + tq;
        vf[j] = *(const bf16x8*)(Vc + R * 64 + (((k2 * 4 + qd) ^ (R & 7)) * 8));
      }
      #pragma unroll
      for (int i = 0; i < 4; ++i)
        #pragma unroll
        for (int j = 0; j < 4; ++j)
          acc_h[i][j] = __builtin_amdgcn_mfma_f32_16x16x32_bf16(pf[i], vf[j], acc_h[i][j], 0, 0, 0);
    }
    __builtin_amdgcn_s_setprio(0);
  }

  // ---- epilogue: Hp[b][qx*128 + q][h*128 + dv] ----
  unsigned short* Hb = Hp + (size_t)b * 1048576 + (size_t)qx * 131072 + h * 128;
  #pragma unroll
  for (int i = 0; i < 4; ++i) {
    const int q0 = wm * 64 + i * 16 + qd * 4;
    #pragma unroll
    for (int j = 0; j < 4; ++j) {
      const int dv = wn * 64 + j * 16 + tq;
      #pragma unroll
      for (int rr = 0; rr < 4; ++rr)
        Hb[(size_t)(q0 + rr) * 1024 + dv] = f2bf(acc_h[i][j][rr]);
    }
  }
}

extern "C" void kernel_launch(void* const* d_in, const int* in_sizes, int n_in,
                              void* d_out, int out_size, void* d_ws, size_t ws_size,
                              hipStream_t stream) {
  const float* x    = (const float*)d_in[0];   // [8,1024,1024]  (B,D,L)
  const float* mask = (const float*)d_in[1];   // [8,1024]
  const float* Wq   = (const float*)d_in[2];   // [8,1024,128]
  const float* Wk   = (const float*)d_in[3];
  const float* Wv   = (const float*)d_in[4];
  const float* Wo   = (const float*)d_in[5];   // [1024,1024]
  float* out = (float*)d_out;                  // [8,1024,1024]  (B,D,L)

  char* p = (char*)d_ws;
  unsigned short* xt    = (unsigned short*)p; p += 16777216;  // [b][l][d] bf16
  unsigned short* WqkvT = (unsigned short*)p; p += 6291456;   // [24 heads][128][1024]
  unsigned short* Wot   = (unsigned short*)p; p += 2097152;   // [j][i]
  unsigned short* QKV   = (unsigned short*)p; p += 50331648;  // [b][24h][l][128]; V region holds V'n after vnorm
  unsigned short* Vpu   = (unsigned short*)p; p += 16777216;  // [b][h][dv][l] (unnormalized V^T)
  unsigned short* Hp    = (unsigned short*)p; p += 16777216;  // [b][l][h*128+dv]
  float* colsum = (float*)p; p += 262144;                     // [64][1024] fp32

  hipMemsetAsync(colsum, 0, 262144, stream);

  // prologue: transposes
  transpose_x_wo<<<dim3(16, 16, 9), 256, 0, stream>>>(x, Wo, xt, Wot);
  transpose_w24<<<dim3(2, 16, 24), 256, 0, stream>>>(Wq, Wk, Wv, WqkvT);

  // QKV[b][gh][l][dk] = xt[b] * WqkvT[gh]^T ; V-heads (gh>=16) written
  // transposed (unnormalized) into Vpu.
  gemm_tn<false><<<dim3(1, 8, 192), 256, 0, stream>>>(
      xt, WqkvT, (void*)QKV, 1024, 1024, 1024, 128, 1.f,
      0L, 1048576L, 0L,  0L, 0L, 131072L,  0L, 3145728L, 131072L, 0, 24, Vpu);

  // pass 1: colsum (raw-barrier pipelined, LDS partials, epilogue atomics)
  scores_colsum<<<dim3(512, 1, 1), 256, 0, stream>>>(QKV, colsum, mask);

  // V'n = V' / colsum  -> QKV's V region
  vnorm<<<dim3(64, 64, 1), 256, 0, stream>>>(Vpu, QKV, colsum);

  // pass 2: fused scores-recompute + PV (clean counted vmcnt)
  attn_pv_fused<<<dim3(512, 1, 1), 256, 0, stream>>>(QKV, Hp, mask);

  // out[b][j][l] = Wot[j,:] . H[b][l,:]
  gemm_tn<true><<<dim3(8, 8, 8), 256, 0, stream>>>(
      Wot, Hp, (void*)out, 1024, 1024, 1024, 1024, 1.f,
      0L, 0L, 0L,  0L, 1048576L, 0L,  0L, 1048576L, 0L, 0, 1, nullptr);
}

// Round 10
// 259.727 us; speedup vs baseline: 1.7174x; 1.0312x over previous
//
#include <hip/hip_runtime.h>

typedef short bf16x8 __attribute__((ext_vector_type(8)));
typedef float f32x4 __attribute__((ext_vector_type(4)));
typedef unsigned short u16x8 __attribute__((ext_vector_type(8)));

#define MASK_NEG (-1e30f)

__device__ __forceinline__ unsigned short f2bf(float f) {
  union { float f; unsigned u; } v; v.f = f;
  unsigned r = v.u + 0x7fffu + ((v.u >> 16) & 1u);
  return (unsigned short)(r >> 16);
}

__device__ __forceinline__ float bf2f(unsigned short u) {
  union { unsigned u; float f; } v; v.u = ((unsigned)u) << 16;
  return v.f;
}

__device__ __forceinline__ void gl_lds16(const void* g, void* l) {
  __builtin_amdgcn_global_load_lds(
      (__attribute__((address_space(1))) void*)(void*)g,
      (__attribute__((address_space(3))) void*)l, 16, 0, 0);
}

// -------- shared transpose body: dst[c][r] = bf16(src[r][c]), 64x64 tile ----
__device__ __forceinline__ void transpose_tile(
    const float* __restrict__ s, unsigned short* __restrict__ d,
    int R, int C, int x0, int y0, int t, float tile[64][65]) {
  {
    const int r = t >> 4, c4 = (t & 15) * 4;
    for (int it = 0; it < 4; ++it) {
      const int rr = r + it * 16;
      const float4 v = *(const float4*)(s + (size_t)(y0 + rr) * C + x0 + c4);
      tile[rr][c4 + 0] = v.x; tile[rr][c4 + 1] = v.y;
      tile[rr][c4 + 2] = v.z; tile[rr][c4 + 3] = v.w;
    }
  }
  __syncthreads();
  {
    const int cc = t >> 4, r4 = (t & 15) * 4;
    for (int it = 0; it < 4; ++it) {
      const int c = cc + it * 16;
      ushort4 o;
      o.x = f2bf(tile[r4 + 0][c]); o.y = f2bf(tile[r4 + 1][c]);
      o.z = f2bf(tile[r4 + 2][c]); o.w = f2bf(tile[r4 + 3][c]);
      *(ushort4*)(d + (size_t)(x0 + c) * R + y0 + r4) = o;
    }
  }
}

// -------- transpose x (8 batches) + Wo, all 1024x1024, one dispatch --------
__global__ __launch_bounds__(256) void transpose_x_wo(
    const float* __restrict__ x, const float* __restrict__ Wo,
    unsigned short* __restrict__ xt, unsigned short* __restrict__ Wot) {
  __shared__ float tile[64][65];
  const int z = blockIdx.z;   // 0..7: x batch, 8: Wo
  const float* s = (z < 8) ? (x + (size_t)z * 1048576) : Wo;
  unsigned short* d = (z < 8) ? (xt + (size_t)z * 1048576) : Wot;
  transpose_tile(s, d, 1024, 1024, blockIdx.x * 64, blockIdx.y * 64,
                 threadIdx.x, tile);
}

// -------- transpose all 24 per-head W matrices (1024x128) in one dispatch ---
__global__ __launch_bounds__(256) void transpose_w24(
    const float* __restrict__ Wq, const float* __restrict__ Wk,
    const float* __restrict__ Wv, unsigned short* __restrict__ WqkvT) {
  __shared__ float tile[64][65];
  const int z = blockIdx.z;   // 0..23
  const int sel = z >> 3, h = z & 7;
  const float* base = (sel == 0) ? Wq : (sel == 1) ? Wk : Wv;
  const float* s = base + (size_t)h * 131072;
  unsigned short* d = WqkvT + (size_t)z * 131072;
  transpose_tile(s, d, 1024, 128, blockIdx.x * 64, blockIdx.y * 64,
                 threadIdx.x, tile);
}

// -------- generic bf16 MFMA GEMM, BK=64 (m97 staging) -----------------------
template<bool F32OUT>
__global__ __launch_bounds__(256) void gemm_tn(
    const unsigned short* __restrict__ A, const unsigned short* __restrict__ B,
    void* __restrict__ Cv,
    int K, int ldA, int ldB, int ldC, float scale,
    long sAl, long sAb, long sAh,
    long sBl, long sBb, long sBh,
    long sCl, long sCb, long sCh,
    int zbase, int zdiv, unsigned short* __restrict__ Vt)
{
  __shared__ unsigned short As[128 * 64];   // [128 rows][64 k], chunk-swizzled
  __shared__ unsigned short Bs[128 * 64];
  int bx, by, bz;
  {
    const int nx = gridDim.x, ny = gridDim.y;
    const int nwg = nx * ny * gridDim.z;
    int flat = blockIdx.x + nx * (blockIdx.y + ny * blockIdx.z);
    if ((nwg & 7) == 0) flat = (flat & 7) * (nwg >> 3) + (flat >> 3);
    bx = flat % nx; flat /= nx;
    by = flat % ny; bz = flat / ny;
  }
  const int z = bz;
  const int g = zbase + z;
  const int gb = g / zdiv, gh = g % zdiv;
  const unsigned short* Ab = A + (size_t)z * sAl + (size_t)gb * sAb + (size_t)gh * sAh;
  const unsigned short* Bb = B + (size_t)z * sBl + (size_t)gb * sBb + (size_t)gh * sBh;
  const int m0 = by * 128, n0 = bx * 128;
  const int t = threadIdx.x;
  const int lane = t & 63;
  const int wave = t >> 6;
  const int wm = wave >> 1, wn = wave & 1;

  const int sr2 = t >> 3;          // 0..31
  const int ss8 = t & 7;
  const int sq8 = ss8 ^ (sr2 & 7);

  const unsigned short* ap0 = Ab + (size_t)(m0 +  0 + sr2) * ldA + sq8 * 8;
  const unsigned short* ap1 = Ab + (size_t)(m0 + 32 + sr2) * ldA + sq8 * 8;
  const unsigned short* ap2 = Ab + (size_t)(m0 + 64 + sr2) * ldA + sq8 * 8;
  const unsigned short* ap3 = Ab + (size_t)(m0 + 96 + sr2) * ldA + sq8 * 8;
  const unsigned short* bp0 = Bb + (size_t)(n0 +  0 + sr2) * ldB + sq8 * 8;
  const unsigned short* bp1 = Bb + (size_t)(n0 + 32 + sr2) * ldB + sq8 * 8;
  const unsigned short* bp2 = Bb + (size_t)(n0 + 64 + sr2) * ldB + sq8 * 8;
  const unsigned short* bp3 = Bb + (size_t)(n0 + 96 + sr2) * ldB + sq8 * 8;

  char* asd0 = (char*)As +     0 + t * 16;
  char* asd1 = (char*)As +  4096 + t * 16;
  char* asd2 = (char*)As +  8192 + t * 16;
  char* asd3 = (char*)As + 12288 + t * 16;
  char* bsd0 = (char*)Bs +     0 + t * 16;
  char* bsd1 = (char*)Bs +  4096 + t * 16;
  char* bsd2 = (char*)Bs +  8192 + t * 16;
  char* bsd3 = (char*)Bs + 12288 + t * 16;

  const int tq = lane & 15, qd = lane >> 4;

  f32x4 acc[4][4];
  #pragma unroll
  for (int i = 0; i < 4; ++i)
    #pragma unroll
    for (int j = 0; j < 4; ++j)
      acc[i][j] = f32x4{0.f, 0.f, 0.f, 0.f};

  const int kIters = K >> 6;
  for (int kt = 0; kt < kIters; ++kt) {
    __syncthreads();
    gl_lds16(ap0, asd0); gl_lds16(ap1, asd1);
    gl_lds16(ap2, asd2); gl_lds16(ap3, asd3);
    gl_lds16(bp0, bsd0); gl_lds16(bp1, bsd1);
    gl_lds16(bp2, bsd2); gl_lds16(bp3, bsd3);
    ap0 += 64; ap1 += 64; ap2 += 64; ap3 += 64;
    bp0 += 64; bp1 += 64; bp2 += 64; bp3 += 64;
    __builtin_amdgcn_s_waitcnt(0x0f70);    // vmcnt(0)
    __syncthreads();

    #pragma unroll
    for (int kk = 0; kk < 2; ++kk) {
      bf16x8 af[4], bfr[4];
      #pragma unroll
      for (int i = 0; i < 4; ++i) {
        const int R = wm * 64 + i * 16 + tq;
        const int slot = (kk * 4 + qd) ^ (R & 7);
        af[i] = *(const bf16x8*)(As + R * 64 + slot * 8);
      }
      #pragma unroll
      for (int j = 0; j < 4; ++j) {
        const int R = wn * 64 + j * 16 + tq;
        const int slot = (kk * 4 + qd) ^ (R & 7);
        bfr[j] = *(const bf16x8*)(Bs + R * 64 + slot * 8);
      }
      #pragma unroll
      for (int i = 0; i < 4; ++i)
        #pragma unroll
        for (int j = 0; j < 4; ++j)
          acc[i][j] = __builtin_amdgcn_mfma_f32_16x16x32_bf16(af[i], bfr[j], acc[i][j], 0, 0, 0);
    }
  }

  if (!F32OUT && Vt != nullptr && gh >= 16) {
    // V-head: write transposed bf16 -> Vt[(gb*8+gh-16)][dv=col][l=row]
    unsigned short* Vb = Vt + (size_t)(gb * 8 + (gh - 16)) * 131072;
    #pragma unroll
    for (int i = 0; i < 4; ++i) {
      const int row = m0 + wm * 64 + i * 16 + qd * 4;   // l (multiple of 4)
      #pragma unroll
      for (int j = 0; j < 4; ++j) {
        const int col = n0 + wn * 64 + j * 16 + tq;     // dv
        ushort4 o;
        o.x = f2bf(acc[i][j][0] * scale);
        o.y = f2bf(acc[i][j][1] * scale);
        o.z = f2bf(acc[i][j][2] * scale);
        o.w = f2bf(acc[i][j][3] * scale);
        *(ushort4*)(Vb + (size_t)col * 1024 + row) = o;
      }
    }
    return;
  }

  const size_t cOff = (size_t)z * sCl + (size_t)gb * sCb + (size_t)gh * sCh;
  #pragma unroll
  for (int i = 0; i < 4; ++i) {
    const int row = m0 + wm * 64 + i * 16 + qd * 4;   // C/D: row=(lane>>4)*4+reg
    #pragma unroll
    for (int j = 0; j < 4; ++j) {
      const int col = n0 + wn * 64 + j * 16 + tq;     // C/D: col=lane&15
      if constexpr (F32OUT) {
        float* C = (float*)Cv + cOff;
        #pragma unroll
        for (int rr = 0; rr < 4; ++rr)
          C[(size_t)(row + rr) * ldC + col] = acc[i][j][rr] * scale;
      } else {
        unsigned short* C = (unsigned short*)Cv + cOff;
        #pragma unroll
        for (int rr = 0; rr < 4; ++rr)
          C[(size_t)(row + rr) * ldC + col] = f2bf(acc[i][j][rr] * scale);
      }
    }
  }
}

// -------- pass 1: strip-mined QK^T + exp + query-axis column sums ----------
// One block per (bh, 128-q strip). Q staged once through the K-dbuf window
// (LDS 40 KB total -> 3 blocks/CU); K tiles (64x128) double-buffered with
// RAW s_barrier + counted vmcnt. LDS colsum partials; one atomic pass at end.
__global__ __launch_bounds__(256, 3) void scores_colsum(
    const unsigned short* __restrict__ QKV, float* __restrict__ colsum,
    const float* __restrict__ mask)
{
  __shared__ unsigned short lds[16384];   // 32 KB: Q prologue; then K dbuf 2x16KB
  __shared__ float csacc[2][1024];        // per-wm colsum partials (8 KB)

  const int bid = blockIdx.x;             // 512 blocks; XCD chunk = 8 bh
  const int w = ((bid & 7) << 6) | (bid >> 3);
  const int g = w >> 3, qx = w & 7;
  const int b = g >> 3, h = g & 7;
  const unsigned short* Qg = QKV + (size_t)b * 3145728 + (size_t)h * 131072
                                 + (size_t)qx * 16384;
  const unsigned short* Kg = QKV + (size_t)b * 3145728 + (size_t)(8 + h) * 131072;

  const int t = threadIdx.x;
  const int lane = t & 63, wave = t >> 6;
  const int wm = wave >> 1, wn = wave & 1;
  const int tq = lane & 15, qd = lane >> 4;

  // prologue: stage Q [128][128] into the full 32 KB window
  #pragma unroll
  for (int it = 0; it < 8; ++it) {
    const int c = it * 256 + t;
    const int row = c >> 4;
    const int src = (c ^ (c >> 4)) & 15;
    gl_lds16(Qg + (size_t)row * 128 + src * 8, (char*)lds + c * 16);
  }
  __builtin_amdgcn_s_waitcnt(0x0f70);    // vmcnt(0)
  __syncthreads();

  bf16x8 qf[4][4];
  #pragma unroll
  for (int i = 0; i < 4; ++i) {
    const int R = wm * 64 + i * 16 + tq;
    #pragma unroll
    for (int kk = 0; kk < 4; ++kk)
      qf[i][kk] = *(const bf16x8*)(lds + R * 128 + (((kk * 4 + qd) ^ (R & 15)) * 8));
  }
  __syncthreads();   // all qf reads done; window becomes K dbuf

  // stage K-tile 0 into slot0 (bytes 0..16K)
  #pragma unroll
  for (int it = 0; it < 4; ++it) {
    const int c = it * 256 + t;
    const int row = c >> 4;
    const int src = (c ^ (c >> 4)) & 15;
    gl_lds16(Kg + (size_t)row * 128 + src * 8, (char*)lds + c * 16);
  }

  const float scl = 0.08838834764831845f;  // 1/sqrt(128)
  float aq[4][4];
  {
    const float* mrow = mask + (size_t)b * 1024 + qx * 128;
    #pragma unroll
    for (int i = 0; i < 4; ++i) {
      const float4 m4 = *(const float4*)(mrow + wm * 64 + i * 16 + qd * 4);
      aq[i][0] = (1.f - m4.x) * MASK_NEG - 20.f;
      aq[i][1] = (1.f - m4.y) * MASK_NEG - 20.f;
      aq[i][2] = (1.f - m4.z) * MASK_NEG - 20.f;
      aq[i][3] = (1.f - m4.w) * MASK_NEG - 20.f;
    }
  }

  for (int kt = 0; kt < 16; ++kt) {
    __builtin_amdgcn_s_barrier();        // B1: target slot's readers done
    __builtin_amdgcn_sched_barrier(0);
    if (kt < 15) {
      unsigned short* Kn = ((kt + 1) & 1) ? (lds + 8192) : lds;
      const unsigned short* Kgn = Kg + (size_t)(kt + 1) * 8192;
      #pragma unroll
      for (int it = 0; it < 4; ++it) {
        const int c = it * 256 + t;
        const int row = c >> 4;
        const int src = (c ^ (c >> 4)) & 15;
        gl_lds16(Kgn + (size_t)row * 128 + src * 8, (char*)Kn + c * 16);
      }
      asm volatile("s_waitcnt vmcnt(4)" ::: "memory");   // kt's K landed
    } else {
      asm volatile("s_waitcnt vmcnt(0)" ::: "memory");
    }
    __builtin_amdgcn_s_barrier();        // B2: tile kt visible to all
    __builtin_amdgcn_sched_barrier(0);

    const unsigned short* Kc = (kt & 1) ? (lds + 8192) : lds;
    f32x4 acc_s[4][2];
    #pragma unroll
    for (int i = 0; i < 4; ++i)
      #pragma unroll
      for (int j = 0; j < 2; ++j)
        acc_s[i][j] = f32x4{0.f, 0.f, 0.f, 0.f};
    __builtin_amdgcn_s_setprio(1);
    #pragma unroll
    for (int kk = 0; kk < 4; ++kk) {
      bf16x8 kf[2];
      #pragma unroll
      for (int j = 0; j < 2; ++j) {
        const int R = wn * 32 + j * 16 + tq;
        kf[j] = *(const bf16x8*)(Kc + R * 128 + (((kk * 4 + qd) ^ (R & 15)) * 8));
      }
      #pragma unroll
      for (int i = 0; i < 4; ++i)
        #pragma unroll
        for (int j = 0; j < 2; ++j)
          acc_s[i][j] = __builtin_amdgcn_mfma_f32_16x16x32_bf16(qf[i][kk], kf[j], acc_s[i][j], 0, 0, 0);
    }
    __builtin_amdgcn_s_setprio(0);

    float cp0 = 0.f, cp1 = 0.f;
    #pragma unroll
    for (int i = 0; i < 4; ++i)
      #pragma unroll
      for (int rr = 0; rr < 4; ++rr) {
        cp0 += __expf(acc_s[i][0][rr] * scl + aq[i][rr]);
        cp1 += __expf(acc_s[i][1][rr] * scl + aq[i][rr]);
      }
    cp0 += __shfl_xor(cp0, 16, 64); cp0 += __shfl_xor(cp0, 32, 64);
    cp1 += __shfl_xor(cp1, 16, 64); cp1 += __shfl_xor(cp1, 32, 64);
    if (qd == 0) {                       // each entry written exactly once
      csacc[wm][kt * 64 + wn * 32 + tq] = cp0;
      csacc[wm][kt * 64 + wn * 32 + 16 + tq] = cp1;
    }
  }

  __syncthreads();                       // csacc complete (full drain, once)
  float* cs = colsum + (size_t)g * 1024;
  #pragma unroll
  for (int r = 0; r < 4; ++r) {
    const int idx = r * 256 + t;
    atomicAdd(&cs[idx], csacc[0][idx] + csacc[1][idx]);
  }
}

// -------- vnorm: Vpn[b][16+h][dv][l] = Vpu[g][dv][l] / colsum[g][l] --------
__global__ __launch_bounds__(256) void vnorm(
    const unsigned short* __restrict__ Vpu, unsigned short* __restrict__ QKV,
    const float* __restrict__ colsum)
{
  const int g = blockIdx.y;               // 0..63
  const int b = g >> 3, h = g & 7;
  const unsigned short* S = Vpu + (size_t)g * 131072;
  unsigned short* D = QKV + (size_t)b * 3145728 + (size_t)(16 + h) * 131072;
  const float* cs = colsum + (size_t)g * 1024;
  const int off = (blockIdx.x * 256 + threadIdx.x) * 8;   // 64 x-blocks
  const int l0 = off & 1023;
  const u16x8 v = *(const u16x8*)(S + off);
  const float4 c0 = *(const float4*)(cs + l0);
  const float4 c1 = *(const float4*)(cs + l0 + 4);
  u16x8 o;
  o[0] = f2bf(bf2f(v[0]) / c0.x); o[1] = f2bf(bf2f(v[1]) / c0.y);
  o[2] = f2bf(bf2f(v[2]) / c0.z); o[3] = f2bf(bf2f(v[3]) / c0.w);
  o[4] = f2bf(bf2f(v[4]) / c1.x); o[5] = f2bf(bf2f(v[5]) / c1.y);
  o[6] = f2bf(bf2f(v[6]) / c1.z); o[7] = f2bf(bf2f(v[7]) / c1.w);
  *(u16x8*)(D + off) = o;
}

// -------- pass 2: fused scores-recompute + P*V'n accumulation --------------
// K/V double-buffered; RAW s_barrier + counted vmcnt; the ONLY VMEM in the
// loop is the 8 prefetch global_load_lds, so vmcnt(12)/(8) are honest counts
// and the prefetch truly stays in flight across all three barriers.
__global__ __launch_bounds__(256, 2) void attn_pv_fused(
    const unsigned short* __restrict__ QKV,
    unsigned short* __restrict__ Hp, const float* __restrict__ mask)
{
  __shared__ unsigned short lds[40960];   // 80 KB (element offsets below)
  unsigned short* Ps = lds;               // [128][64] sw8, bytes 0..16K
  // K dbuf: slot0 = lds+16384 (bytes 32K..48K), slot1 = lds+8192 (16K..32K)
  // V dbuf: slot0 = lds+24576 (48K..64K),       slot1 = lds+32768 (64K..80K)
  // Qs prologue = lds[0..16384 elems) = bytes 0..32K (overlays Ps + K slot1)
  unsigned short* Qs = lds;

  const int bid = blockIdx.x;             // 512 blocks; XCD chunk = 8 bh
  const int w = ((bid & 7) << 6) | (bid >> 3);
  const int g = w >> 3, qx = w & 7;
  const int b = g >> 3, h = g & 7;
  const unsigned short* Qg = QKV + (size_t)b * 3145728 + (size_t)h * 131072
                                 + (size_t)qx * 16384;
  const unsigned short* Kg = QKV + (size_t)b * 3145728 + (size_t)(8 + h) * 131072;
  const unsigned short* Vg = QKV + (size_t)b * 3145728 + (size_t)(16 + h) * 131072;

  const int t = threadIdx.x;
  const int lane = t & 63, wave = t >> 6;
  const int wm = wave >> 1, wn = wave & 1;
  const int tq = lane & 15, qd = lane >> 4;

  // ---- prologue: stage Q + K0 + V0 ----
  #pragma unroll
  for (int it = 0; it < 8; ++it) {
    const int c = it * 256 + t;
    const int row = c >> 4;
    const int src = (c ^ (c >> 4)) & 15;
    gl_lds16(Qg + (size_t)row * 128 + src * 8, (char*)Qs + c * 16);
  }
  #pragma unroll
  for (int it = 0; it < 4; ++it) {
    const int c = it * 256 + t;
    const int row = c >> 4;
    const int src = (c ^ (c >> 4)) & 15;
    gl_lds16(Kg + (size_t)row * 128 + src * 8, (char*)(lds + 16384) + c * 16);
  }
  #pragma unroll
  for (int it = 0; it < 4; ++it) {
    const int c = it * 256 + t;
    const int row = c >> 3;
    const int src = (c ^ (c >> 3)) & 7;
    gl_lds16(Vg + (size_t)row * 1024 + src * 8, (char*)(lds + 24576) + c * 16);
  }
  __builtin_amdgcn_s_waitcnt(0x0f70);    // vmcnt(0)
  __syncthreads();

  bf16x8 qf[4][4];
  #pragma unroll
  for (int i = 0; i < 4; ++i) {
    const int R = wm * 64 + i * 16 + tq;
    #pragma unroll
    for (int kk = 0; kk < 4; ++kk)
      qf[i][kk] = *(const bf16x8*)(Qs + R * 128 + (((kk * 4 + qd) ^ (R & 15)) * 8));
  }
  __syncthreads();   // Qs dead; region becomes Ps + K slot1

  f32x4 acc_h[4][4];
  #pragma unroll
  for (int i = 0; i < 4; ++i)
    #pragma unroll
    for (int j = 0; j < 4; ++j)
      acc_h[i][j] = f32x4{0.f, 0.f, 0.f, 0.f};

  const float scl = 0.08838834764831845f;  // 1/sqrt(128)
  float aq[4][4];
  {
    const float* mrow = mask + (size_t)b * 1024 + qx * 128;
    #pragma unroll
    for (int i = 0; i < 4; ++i) {
      const float4 m4 = *(const float4*)(mrow + wm * 64 + i * 16 + qd * 4);
      aq[i][0] = (1.f - m4.x) * MASK_NEG - 20.f;
      aq[i][1] = (1.f - m4.y) * MASK_NEG - 20.f;
      aq[i][2] = (1.f - m4.z) * MASK_NEG - 20.f;
      aq[i][3] = (1.f - m4.w) * MASK_NEG - 20.f;
    }
  }

  for (int kt = 0; kt < 16; ++kt) {
    __builtin_amdgcn_s_barrier();        // B1: target bufs' readers done
    __builtin_amdgcn_sched_barrier(0);
    if (kt < 15) {
      unsigned short* Kn = ((kt + 1) & 1) ? (lds + 8192) : (lds + 16384);
      unsigned short* Vn = ((kt + 1) & 1) ? (lds + 32768) : (lds + 24576);
      const unsigned short* Kgn = Kg + (size_t)(kt + 1) * 8192;
      #pragma unroll
      for (int it = 0; it < 4; ++it) {
        const int c = it * 256 + t;
        const int row = c >> 4;
        const int src = (c ^ (c >> 4)) & 15;
        gl_lds16(Kgn + (size_t)row * 128 + src * 8, (char*)Kn + c * 16);
      }
      #pragma unroll
      for (int it = 0; it < 4; ++it) {
        const int c = it * 256 + t;
        const int row = c >> 3;
        const int src = (c ^ (c >> 3)) & 7;
        gl_lds16(Vg + (size_t)row * 1024 + (kt + 1) * 64 + src * 8, (char*)Vn + c * 16);
      }
      asm volatile("s_waitcnt vmcnt(12)" ::: "memory");   // kt's K landed
    } else {
      asm volatile("s_waitcnt vmcnt(4)" ::: "memory");    // K15 landed
    }
    __builtin_amdgcn_s_barrier();        // B2: K(kt) visible to all
    __builtin_amdgcn_sched_barrier(0);

    const unsigned short* Kc = (kt & 1) ? (lds + 8192) : (lds + 16384);
    const unsigned short* Vc = (kt & 1) ? (lds + 32768) : (lds + 24576);

    // ---- S = Q * K^T : per-wave quadrant [64 q][32 k] ----
    f32x4 acc_s[4][2];
    #pragma unroll
    for (int i = 0; i < 4; ++i)
      #pragma unroll
      for (int j = 0; j < 2; ++j)
        acc_s[i][j] = f32x4{0.f, 0.f, 0.f, 0.f};
    __builtin_amdgcn_s_setprio(1);
    #pragma unroll
    for (int kk = 0; kk < 4; ++kk) {
      bf16x8 kf[2];
      #pragma unroll
      for (int j = 0; j < 2; ++j) {
        const int R = wn * 32 + j * 16 + tq;
        kf[j] = *(const bf16x8*)(Kc + R * 128 + (((kk * 4 + qd) ^ (R & 15)) * 8));
      }
      #pragma unroll
      for (int i = 0; i < 4; ++i)
        #pragma unroll
        for (int j = 0; j < 2; ++j)
          acc_s[i][j] = __builtin_amdgcn_mfma_f32_16x16x32_bf16(qf[i][kk], kf[j], acc_s[i][j], 0, 0, 0);
    }
    __builtin_amdgcn_s_setprio(0);

    // ---- P = exp(S') -> LDS (bf16, 8-slot swizzle); V'n is pre-normalized --
    #pragma unroll
    for (int i = 0; i < 4; ++i) {
      const int q0 = wm * 64 + i * 16 + qd * 4;
      #pragma unroll
      for (int rr = 0; rr < 4; ++rr) {
        const int q = q0 + rr;
        #pragma unroll
        for (int j = 0; j < 2; ++j) {
          const int kl = wn * 32 + j * 16 + tq;
          const float e = __expf(acc_s[i][j][rr] * scl + aq[i][rr]);
          Ps[q * 64 + ((((kl >> 3) ^ (q & 7)) * 8) | (kl & 7))] = f2bf(e);
        }
      }
    }
    if (kt < 15)
      asm volatile("s_waitcnt vmcnt(8) lgkmcnt(0)" ::: "memory");  // V(kt)+P
    else
      asm volatile("s_waitcnt vmcnt(0) lgkmcnt(0)" ::: "memory");
    __builtin_amdgcn_s_barrier();        // B3: V(kt) + P visible
    __builtin_amdgcn_sched_barrier(0);

    // ---- H += P * V'^T : per-wave [64 q][64 dv], contraction 64 ----
    __builtin_amdgcn_s_setprio(1);
    #pragma unroll
    for (int k2 = 0; k2 < 2; ++k2) {
      bf16x8 pf[4], vf[4];
      #pragma unroll
      for (int i = 0; i < 4; ++i) {
        const int R = wm * 64 + i * 16 + tq;
        pf[i] = *(const bf16x8*)(Ps + R * 64 + (((k2 * 4 + qd) ^ (R & 7)) * 8));
      }
      #pragma unroll
      for (int j = 0; j < 4; ++j) {
        const int R = wn * 64 + j * 16 + tq;
        vf[j] = *(const bf16x8*)(Vc + R * 64 + (((k2 * 4 + qd) ^ (R & 7)) * 8));
      }
      #pragma unroll
      for (int i = 0; i < 4; ++i)
        #pragma unroll
        for (int j = 0; j < 4; ++j)
          acc_h[i][j] = __builtin_amdgcn_mfma_f32_16x16x32_bf16(pf[i], vf[j], acc_h[i][j], 0, 0, 0);
    }
    __builtin_amdgcn_s_setprio(0);
  }

  // ---- epilogue: Hp[b][qx*128 + q][h*128 + dv] ----
  unsigned short* Hb = Hp + (size_t)b * 1048576 + (size_t)qx * 131072 + h * 128;
  #pragma unroll
  for (int i = 0; i < 4; ++i) {
    const int q0 = wm * 64 + i * 16 + qd * 4;
    #pragma unroll
    for (int j = 0; j < 4; ++j) {
      const int dv = wn * 64 + j * 16 + tq;
      #pragma unroll
      for (int rr = 0; rr < 4; ++rr)
        Hb[(size_t)(q0 + rr) * 1024 + dv] = f2bf(acc_h[i][j][rr]);
    }
  }
}

extern "C" void kernel_launch(void* const* d_in, const int* in_sizes, int n_in,
                              void* d_out, int out_size, void* d_ws, size_t ws_size,
                              hipStream_t stream) {
  const float* x    = (const float*)d_in[0];   // [8,1024,1024]  (B,D,L)
  const float* mask = (const float*)d_in[1];   // [8,1024]
  const float* Wq   = (const float*)d_in[2];   // [8,1024,128]
  const float* Wk   = (const float*)d_in[3];
  const float* Wv   = (const float*)d_in[4];
  const float* Wo   = (const float*)d_in[5];   // [1024,1024]
  float* out = (float*)d_out;                  // [8,1024,1024]  (B,D,L)

  char* p = (char*)d_ws;
  unsigned short* xt    = (unsigned short*)p; p += 16777216;  // [b][l][d] bf16
  unsigned short* WqkvT = (unsigned short*)p; p += 6291456;   // [24 heads][128][1024]
  unsigned short* Wot   = (unsigned short*)p; p += 2097152;   // [j][i]
  unsigned short* QKV   = (unsigned short*)p; p += 50331648;  // [b][24h][l][128]; V region holds V'n after vnorm
  unsigned short* Vpu   = (unsigned short*)p; p += 16777216;  // [b][h][dv][l] (unnormalized V^T)
  unsigned short* Hp    = (unsigned short*)p; p += 16777216;  // [b][l][h*128+dv]
  float* colsum = (float*)p; p += 262144;                     // [64][1024] fp32

  hipMemsetAsync(colsum, 0, 262144, stream);

  // prologue: transposes
  transpose_x_wo<<<dim3(16, 16, 9), 256, 0, stream>>>(x, Wo, xt, Wot);
  transpose_w24<<<dim3(2, 16, 24), 256, 0, stream>>>(Wq, Wk, Wv, WqkvT);

  // QKV[b][gh][l][dk] = xt[b] * WqkvT[gh]^T ; V-heads (gh>=16) written
  // transposed (unnormalized) into Vpu.
  gemm_tn<false><<<dim3(1, 8, 192), 256, 0, stream>>>(
      xt, WqkvT, (void*)QKV, 1024, 1024, 1024, 128, 1.f,
      0L, 1048576L, 0L,  0L, 0L, 131072L,  0L, 3145728L, 131072L, 0, 24, Vpu);

  // pass 1: colsum (raw-barrier pipelined, 40 KB LDS -> 3 blocks/CU)
  scores_colsum<<<dim3(512, 1, 1), 256, 0, stream>>>(QKV, colsum, mask);

  // V'n = V' / colsum  -> QKV's V region
  vnorm<<<dim3(64, 64, 1), 256, 0, stream>>>(Vpu, QKV, colsum);

  // pass 2: fused scores-recompute + PV (round-7 proven version)
  attn_pv_fused<<<dim3(512, 1, 1), 256, 0, stream>>>(QKV, Hp, mask);

  // out[b][j][l] = Wot[j,:] . H[b][l,:]
  gemm_tn<true><<<dim3(8, 8, 8), 256, 0, stream>>>(
      Wot, Hp, (void*)out, 1024, 1024, 1024, 1024, 1.f,
      0L, 0L, 0L,  0L, 1048576L, 0L,  0L, 1048576L, 0L, 0, 1, nullptr);
}